// Round 3
// baseline (978.366 us; speedup 1.0000x reference)
//
#include <hip/hip_runtime.h>
#include <cstdint>
#include <cstddef>

// ---- problem constants (from reference) ----
#define F_INP 78
#define F_MID 156
#define HEADS 2
#define C2    312   // HEADS*F_MID
#define GDIM  128
#define F1D   1024
#define F2D   512

#define NEG_SENTINEL -1e30f

__device__ __forceinline__ float leaky(float v, float s) { return v > 0.f ? v : s * v; }

// ---------------- CSR construction ----------------

__global__ void deg_count_kernel(const int* __restrict__ ei, int* __restrict__ deg, int E) {
    int e = blockIdx.x * blockDim.x + threadIdx.x;
    if (e >= E) return;
    atomicAdd(&deg[ei[E + e]], 1);
}

// single-block exclusive scan: deg[N] -> row_ptr[N+1]
__global__ void scan_kernel(const int* __restrict__ deg, int* __restrict__ row_ptr, int N) {
    __shared__ int sums[1024];
    int tid = threadIdx.x;
    int chunk = (N + 1023) / 1024;
    int start = tid * chunk;
    int end = start + chunk;
    if (start > N) start = N;
    if (end > N) end = N;
    int s = 0;
    for (int i = start; i < end; i++) s += deg[i];
    sums[tid] = s;
    __syncthreads();
    for (int off = 1; off < 1024; off <<= 1) {
        int v = (tid >= off) ? sums[tid - off] : 0;
        __syncthreads();
        sums[tid] += v;
        __syncthreads();
    }
    int run = (tid == 0) ? 0 : sums[tid - 1];
    for (int i = start; i < end; i++) {
        row_ptr[i] = run;
        run += deg[i];
    }
    if (tid == 1023) row_ptr[N] = run;
}

__global__ void copy_cursor_kernel(const int* __restrict__ row_ptr, int* __restrict__ cursor, int N) {
    int i = blockIdx.x * blockDim.x + threadIdx.x;
    if (i < N) cursor[i] = row_ptr[i];
}

// fill col[] (src per CSR slot) and dstpos[] (dst per CSR slot)
__global__ void fill_csr_kernel(const int* __restrict__ ei, int* __restrict__ cursor,
                                int* __restrict__ col, int* __restrict__ dstpos, int E) {
    int e = blockIdx.x * blockDim.x + threadIdx.x;
    if (e >= E) return;
    int s = ei[e], d = ei[E + e];
    int pos = atomicAdd(&cursor[d], 1);
    col[pos] = s;
    dstpos[pos] = d;
}

// dinv[i] = rsqrt(deg_in + 1)   (self-loop included)
__global__ void dinv_kernel(const int* __restrict__ row_ptr, float* __restrict__ dinv, int N) {
    int i = blockIdx.x * blockDim.x + threadIdx.x;
    if (i >= N) return;
    dinv[i] = rsqrtf((float)(row_ptr[i + 1] - row_ptr[i]) + 1.0f);
}

// ---------------- dense layers ----------------

// h_lin = x @ W1   [N,78]@[78,156]; 8 rows per block
__global__ void lin1_kernel(const float* __restrict__ x, const float* __restrict__ W1,
                            float* __restrict__ h_lin, int N) {
    __shared__ float xs[8][F_INP];
    int n0 = blockIdx.x * 8;
    int tid = threadIdx.x; // block 192
    for (int i = tid; i < 8 * F_INP; i += 192) {
        int r = i / F_INP, c = i % F_INP;
        int n = n0 + r;
        xs[r][c] = (n < N) ? x[(size_t)n * F_INP + c] : 0.f;
    }
    __syncthreads();
    if (tid >= F_MID) return;
    float acc[8] = {0,0,0,0,0,0,0,0};
    for (int k = 0; k < F_INP; k++) {
        float w = W1[k * F_MID + tid];
        #pragma unroll
        for (int r = 0; r < 8; r++) acc[r] += xs[r][k] * w;
    }
    for (int r = 0; r < 8; r++) {
        int n = n0 + r;
        if (n < N) h_lin[(size_t)n * F_MID + tid] = acc[r];
    }
}

// g = leaky(h_agg,0.01) @ W2   [N,156]@[156,312]; 8 rows per block
__global__ void lin2_kernel(const float* __restrict__ h_agg, const float* __restrict__ W2,
                            float* __restrict__ g, int N) {
    __shared__ float hs[8][F_MID];
    int n0 = blockIdx.x * 8;
    int tid = threadIdx.x; // block 320
    for (int i = tid; i < 8 * F_MID; i += 320) {
        int r = i / F_MID, c = i % F_MID;
        int n = n0 + r;
        float v = (n < N) ? h_agg[(size_t)n * F_MID + c] : 0.f;
        hs[r][c] = leaky(v, 0.01f);
    }
    __syncthreads();
    if (tid >= C2) return;
    float acc[8] = {0,0,0,0,0,0,0,0};
    for (int k = 0; k < F_MID; k++) {
        float w = W2[k * C2 + tid];
        #pragma unroll
        for (int r = 0; r < 8; r++) acc[r] += hs[r][k] * w;
    }
    for (int r = 0; r < 8; r++) {
        int n = n0 + r;
        if (n < N) g[(size_t)n * C2 + tid] = acc[r];
    }
}

// ---------------- GCN gather (no atomics) ----------------
// h_agg[d,f] = sum_{s in in(d)} h_lin[s,f]*dinv[s]*dinv[d] + h_lin[d,f]*dinv[d]^2 + b1[f]
__global__ void gcn_gather_kernel(const float* __restrict__ h_lin, const int* __restrict__ row_ptr,
                                  const int* __restrict__ col, const float* __restrict__ dinv,
                                  const float* __restrict__ b1, float* __restrict__ h_agg, int N) {
    int wid  = (blockIdx.x * blockDim.x + threadIdx.x) >> 6;
    int lane = threadIdx.x & 63;
    if (wid >= N) return;
    int d  = wid;
    int jb = row_ptr[d], je = row_ptr[d + 1];
    float dd = dinv[d];
    float acc0 = 0.f, acc1 = 0.f, acc2 = 0.f; // f = lane, lane+64, lane+128 (lane<28)
    int j = jb;
    for (; j + 1 < je; j += 2) {   // x2 unroll for MLP
        int sA = col[j], sB = col[j + 1];
        float nA = dinv[sA] * dd, nB = dinv[sB] * dd;
        const float* hA = h_lin + (size_t)sA * F_MID;
        const float* hB = h_lin + (size_t)sB * F_MID;
        acc0 += hA[lane] * nA;
        acc1 += hA[lane + 64] * nA;
        acc0 += hB[lane] * nB;
        acc1 += hB[lane + 64] * nB;
        if (lane < F_MID - 128) {
            acc2 += hA[lane + 128] * nA;
            acc2 += hB[lane + 128] * nB;
        }
    }
    if (j < je) {
        int s = col[j];
        float norm = dinv[s] * dd;
        const float* hs = h_lin + (size_t)s * F_MID;
        acc0 += hs[lane] * norm;
        acc1 += hs[lane + 64] * norm;
        if (lane < F_MID - 128) acc2 += hs[lane + 128] * norm;
    }
    const float* hd = h_lin + (size_t)d * F_MID;
    float sn = dd * dd;
    acc0 += hd[lane] * sn;
    acc1 += hd[lane + 64] * sn;
    if (lane < F_MID - 128) acc2 += hd[lane + 128] * sn;
    float* o = h_agg + (size_t)d * F_MID;
    o[lane]      = acc0 + b1[lane];
    o[lane + 64] = acc1 + b1[lane + 64];
    if (lane < F_MID - 128) o[lane + 128] = acc2 + b1[lane + 128];
}

// ---------------- GAT attention coefficients ----------------
// a_src[n,h], a_dst[n,h]: one wave per (n,h)
__global__ void att_kernel(const float* __restrict__ g, const float* __restrict__ att_src,
                           const float* __restrict__ att_dst, float* __restrict__ a_src,
                           float* __restrict__ a_dst, int N) {
    int wid  = (blockIdx.x * blockDim.x + threadIdx.x) >> 6;
    int lane = threadIdx.x & 63;
    if (wid >= N * 2) return;
    int n = wid >> 1, h = wid & 1;
    const float* grow = g + (size_t)n * C2 + h * F_MID;
    const float* as = att_src + h * F_MID;
    const float* ad = att_dst + h * F_MID;
    float vs = 0.f, vd = 0.f;
    for (int f = lane; f < F_MID; f += 64) {
        float gv = grow[f];
        vs += gv * as[f];
        vd += gv * ad[f];
    }
    #pragma unroll
    for (int off = 32; off; off >>= 1) {
        vs += __shfl_xor(vs, off);
        vd += __shfl_xor(vd, off);
    }
    if (lane == 0) { a_src[wid] = vs; a_dst[wid] = vd; }
}

// ---------------- GAT K1: per-dst online max+sum -> minv[d]=(m0,inv0,m1,inv1) ----------------
__global__ void gat_ms_kernel(const float* __restrict__ a_src, const float* __restrict__ a_dst,
                              const int* __restrict__ row_ptr, const int* __restrict__ col,
                              float4* __restrict__ minv, int N) {
    int wid  = (blockIdx.x * blockDim.x + threadIdx.x) >> 6;
    int lane = threadIdx.x & 63;
    if (wid >= N) return;
    int d  = wid;
    int jb = row_ptr[d], je = row_ptr[d + 1];
    float2 ad = ((const float2*)a_dst)[d];
    float2 asd = ((const float2*)a_src)[d];
    float es0 = leaky(asd.x + ad.x, 0.2f);   // self-loop logits
    float es1 = leaky(asd.y + ad.y, 0.2f);

    float m0 = NEG_SENTINEL, s0 = 0.f, m1 = NEG_SENTINEL, s1 = 0.f;
    for (int j = jb + lane; j < je; j += 64) {
        float2 as = ((const float2*)a_src)[col[j]];
        float e0 = leaky(as.x + ad.x, 0.2f);
        float e1 = leaky(as.y + ad.y, 0.2f);
        float nm0 = fmaxf(m0, e0); s0 = s0 * __expf(m0 - nm0) + __expf(e0 - nm0); m0 = nm0;
        float nm1 = fmaxf(m1, e1); s1 = s1 * __expf(m1 - nm1) + __expf(e1 - nm1); m1 = nm1;
    }
    #pragma unroll
    for (int off = 32; off; off >>= 1) {
        float om0 = __shfl_xor(m0, off), os0 = __shfl_xor(s0, off);
        float om1 = __shfl_xor(m1, off), os1 = __shfl_xor(s1, off);
        float nm0 = fmaxf(m0, om0);
        s0 = s0 * __expf(m0 - nm0) + os0 * __expf(om0 - nm0); m0 = nm0;
        float nm1 = fmaxf(m1, om1);
        s1 = s1 * __expf(m1 - nm1) + os1 * __expf(om1 - nm1); m1 = nm1;
    }
    { // fold self-loop
        float nm0 = fmaxf(m0, es0);
        s0 = s0 * __expf(m0 - nm0) + __expf(es0 - nm0); m0 = nm0;
        float nm1 = fmaxf(m1, es1);
        s1 = s1 * __expf(m1 - nm1) + __expf(es1 - nm1); m1 = nm1;
    }
    if (lane == 0) {
        float4 r; r.x = m0; r.y = 1.0f / s0; r.z = m1; r.w = 1.0f / s1;
        minv[d] = r;
    }
}

// ---------------- GAT K2: per-CSR-slot normalized weights ----------------
__global__ void gat_w_kernel(const float* __restrict__ a_src, const float* __restrict__ a_dst,
                             const int* __restrict__ col, const int* __restrict__ dstpos,
                             const float4* __restrict__ minv, float2* __restrict__ wbuf, int E) {
    int j = blockIdx.x * blockDim.x + threadIdx.x;
    if (j >= E) return;
    int s = col[j], d = dstpos[j];
    float2 as = ((const float2*)a_src)[s];
    float2 ad = ((const float2*)a_dst)[d];
    float4 mv = minv[d];
    float2 w;
    w.x = __expf(leaky(as.x + ad.x, 0.2f) - mv.x) * mv.y;
    w.y = __expf(leaky(as.y + ad.y, 0.2f) - mv.z) * mv.w;
    wbuf[j] = w;
}

// ---------------- GAT K3: weighted gather (no atomics, weights precomputed) ----------------
__global__ void gat_gather_kernel(const float* __restrict__ g, const float* __restrict__ a_src,
                                  const float* __restrict__ a_dst, const int* __restrict__ row_ptr,
                                  const int* __restrict__ col, const float2* __restrict__ wbuf,
                                  const float4* __restrict__ minv, float* __restrict__ gout, int N) {
    int wid  = (blockIdx.x * blockDim.x + threadIdx.x) >> 6;
    int lane = threadIdx.x & 63;
    if (wid >= N) return;
    int d  = wid;
    int jb = row_ptr[d], je = row_ptr[d + 1];
    float acc[5] = {0, 0, 0, 0, 0};

    { // self contribution
        float2 ad = ((const float2*)a_dst)[d];
        float2 asd = ((const float2*)a_src)[d];
        float4 mv = minv[d];
        float w0 = __expf(leaky(asd.x + ad.x, 0.2f) - mv.x) * mv.y;
        float w1 = __expf(leaky(asd.y + ad.y, 0.2f) - mv.z) * mv.w;
        const float* gd = g + (size_t)d * C2;
        #pragma unroll
        for (int k = 0; k < 5; k++) {
            int f = lane + 64 * k;
            if (f < C2) acc[k] = gd[f] * ((f < F_MID) ? w0 : w1);
        }
    }
    int j = jb;
    for (; j + 1 < je; j += 2) {   // x2 unroll: 10 row-loads in flight
        int sA = col[j], sB = col[j + 1];
        float2 wA = wbuf[j], wB = wbuf[j + 1];
        const float* gA = g + (size_t)sA * C2;
        const float* gB = g + (size_t)sB * C2;
        #pragma unroll
        for (int k = 0; k < 5; k++) {
            int f = lane + 64 * k;
            if (f < C2) {
                acc[k] += gA[f] * ((f < F_MID) ? wA.x : wA.y);
                acc[k] += gB[f] * ((f < F_MID) ? wB.x : wB.y);
            }
        }
    }
    if (j < je) {
        int s = col[j];
        float2 w = wbuf[j];
        const float* gs = g + (size_t)s * C2;
        #pragma unroll
        for (int k = 0; k < 5; k++) {
            int f = lane + 64 * k;
            if (f < C2) acc[k] += gs[f] * ((f < F_MID) ? w.x : w.y);
        }
    }
    float* o = gout + (size_t)d * C2;
    #pragma unroll
    for (int k = 0; k < 5; k++) {
        int f = lane + 64 * k;
        if (f < C2) o[f] = acc[k];
    }
}

// ---------------- pooling + MLP ----------------

__global__ void starts_kernel(const int* __restrict__ batch, int* __restrict__ starts, int N, int B) {
    int b = blockIdx.x * blockDim.x + threadIdx.x;
    if (b > B) return;
    if (b == B) { starts[B] = N; return; }
    int lo = 0, hi = N;
    while (lo < hi) {
        int mid = (lo + hi) >> 1;
        if (batch[mid] < b) lo = mid + 1; else hi = mid;
    }
    starts[b] = lo;
}

// p0[b,c] = leaky(max_n gout[n,c] + b2[c], 0.01)   (bias+leaky commute with max)
__global__ void pool_kernel(const float* __restrict__ gout, const float* __restrict__ b2,
                            const int* __restrict__ starts, float* __restrict__ p0) {
    int b = blockIdx.x;
    int c = threadIdx.x; // block 320
    if (c >= C2) return;
    int s = starts[b], e = starts[b + 1];
    float mx = -INFINITY;
    for (int n = s; n < e; n++)
        mx = fmaxf(mx, gout[(size_t)n * C2 + c]);
    p0[b * C2 + c] = leaky(mx + b2[c], 0.01f);
}

// generic dense layer: out[b,c] = act(in[b,:KDIM] . W[:,c] + bias[c])
// ACT: 0 none, 1 leaky 0.01, 2 relu
template <int KDIM, int ACT>
__global__ void fc_kernel(const float* __restrict__ in, const float* __restrict__ W,
                          const float* __restrict__ bias, float* __restrict__ out,
                          int Bn, int OUT) {
    int idx = blockIdx.x * blockDim.x + threadIdx.x;
    if (idx >= Bn * OUT) return;
    int b = idx / OUT, c = idx % OUT;
    const float* irow = in + (size_t)b * KDIM;
    float acc = bias[c];
    #pragma unroll 4
    for (int k = 0; k < KDIM; k++) acc += irow[k] * W[(size_t)k * OUT + c];
    if (ACT == 1) acc = leaky(acc, 0.01f);
    if (ACT == 2) acc = fmaxf(acc, 0.f);
    out[idx] = acc;
}

extern "C" void kernel_launch(void* const* d_in, const int* in_sizes, int n_in,
                              void* d_out, int out_size, void* d_ws, size_t ws_size,
                              hipStream_t stream) {
    const float* x       = (const float*)d_in[0];
    const int*   ei      = (const int*)d_in[1];
    const int*   batch   = (const int*)d_in[2];
    const float* W1      = (const float*)d_in[3];
    const float* b1      = (const float*)d_in[4];
    const float* W2      = (const float*)d_in[5];
    const float* att_src = (const float*)d_in[6];
    const float* att_dst = (const float*)d_in[7];
    const float* b2      = (const float*)d_in[8];
    const float* Wg      = (const float*)d_in[9];
    const float* bg      = (const float*)d_in[10];
    const float* Wf1     = (const float*)d_in[11];
    const float* bf1     = (const float*)d_in[12];
    const float* Wf2     = (const float*)d_in[13];
    const float* bf2     = (const float*)d_in[14];
    const float* Wo      = (const float*)d_in[15];
    const float* bo      = (const float*)d_in[16];
    float* out = (float*)d_out;

    const int N  = in_sizes[0] / F_INP;
    const int E  = in_sizes[1] / 2;
    const int Bn = out_size;          // 128 graphs

    // ---- workspace layout (floats unless noted) ----
    // g region lives the whole pipeline. AA region: h_lin|h_agg early, gout late (alias).
    float* g     = (float*)d_ws;                    // 312N
    float* AA    = g + (size_t)C2 * N;              // 312N
    float* h_lin = AA;                              //   156N (phase 1)
    float* h_agg = AA + (size_t)F_MID * N;          //   156N (phase 1)
    float* gout  = AA;                              //   312N (phase 2, after lin2)
    float4* minv = (float4*)(AA + (size_t)C2 * N);  // N float4
    float* a_src = (float*)(minv + N);              // 2N
    float* a_dst = a_src + 2 * (size_t)N;           // 2N
    float2* wbuf = (float2*)(a_dst + 2 * (size_t)N);// E float2
    float* dinv  = (float*)(wbuf + E);              // N
    int* deg_i   = (int*)(dinv + N);                // N   (zeroed)
    int* row_ptr = deg_i + N;                       // N+1
    int* cursor  = row_ptr + (N + 1);               // N
    int* col     = cursor + N;                      // E
    int* dstpos  = col + E;                         // E
    int* starts  = dstpos + E;                      // Bn+1
    float* p0    = (float*)(starts + (Bn + 1));     // Bn*312
    float* p1    = p0 + (size_t)Bn * C2;            // Bn*128
    float* p2    = p1 + (size_t)Bn * GDIM;          // Bn*1024
    float* p3    = p2 + (size_t)Bn * F1D;           // Bn*512

    hipMemsetAsync(deg_i, 0, (size_t)N * sizeof(int), stream);

    // segment starts (only depends on batch)
    starts_kernel<<<1, 256, 0, stream>>>(batch, starts, N, Bn);

    // CSR build
    deg_count_kernel<<<(E + 255) / 256, 256, 0, stream>>>(ei, deg_i, E);
    scan_kernel<<<1, 1024, 0, stream>>>(deg_i, row_ptr, N);
    copy_cursor_kernel<<<(N + 255) / 256, 256, 0, stream>>>(row_ptr, cursor, N);
    fill_csr_kernel<<<(E + 255) / 256, 256, 0, stream>>>(ei, cursor, col, dstpos, E);
    dinv_kernel<<<(N + 255) / 256, 256, 0, stream>>>(row_ptr, dinv, N);

    // GCN
    lin1_kernel<<<(N + 7) / 8, 192, 0, stream>>>(x, W1, h_lin, N);
    gcn_gather_kernel<<<(N + 3) / 4, 256, 0, stream>>>(h_lin, row_ptr, col, dinv, b1, h_agg, N);

    // GAT
    lin2_kernel<<<(N + 7) / 8, 320, 0, stream>>>(h_agg, W2, g, N);
    att_kernel<<<(2 * N + 3) / 4, 256, 0, stream>>>(g, att_src, att_dst, a_src, a_dst, N);
    gat_ms_kernel<<<(N + 3) / 4, 256, 0, stream>>>(a_src, a_dst, row_ptr, col, minv, N);
    gat_w_kernel<<<(E + 255) / 256, 256, 0, stream>>>(a_src, a_dst, col, dstpos, minv, wbuf, E);
    gat_gather_kernel<<<(N + 3) / 4, 256, 0, stream>>>(g, a_src, a_dst, row_ptr, col, wbuf, minv, gout, N);

    // pool + MLP
    pool_kernel<<<Bn, 320, 0, stream>>>(gout, b2, starts, p0);
    fc_kernel<C2, 1><<<(Bn * GDIM + 255) / 256, 256, 0, stream>>>(p0, Wg, bg, p1, Bn, GDIM);
    fc_kernel<GDIM, 2><<<(Bn * F1D + 255) / 256, 256, 0, stream>>>(p1, Wf1, bf1, p2, Bn, F1D);
    fc_kernel<F1D, 2><<<(Bn * F2D + 255) / 256, 256, 0, stream>>>(p2, Wf2, bf2, p3, Bn, F2D);
    fc_kernel<F2D, 0><<<1, 128, 0, stream>>>(p3, Wo, bo, out, Bn, 1);
}